// Round 1
// baseline (1100.100 us; speedup 1.0000x reference)
//
#include <hip/hip_runtime.h>
#include <stdint.h>

#define AS1 __attribute__((address_space(1)))
#define AS3 __attribute__((address_space(3)))

typedef unsigned short u16;
typedef __attribute__((ext_vector_type(8))) short short8;
typedef __attribute__((ext_vector_type(4))) float f32x4;

#define LOG2PI_F 1.8378770664093453f

// problem constants
#define BQ   16
#define TQ   256
#define DQ   512
#define LQ   51
#define L2Q  2601
#define KQ   1536     // 3*512 (split-bf16: [xh, xl, xh] . [Wh; Wh; Wl])
// column layout of the fused projection (per (b,t) row)
#define C_SW   0      // 51   : s_w                      (identity + bias)
#define C_SMU  51     // 51   : s_mu                     (identity + bias)
#define C_SVAR 102    // 51   : s_var = exp(clip(.))
#define C_TW   153    // 2601 : t_w                      (identity + bias)
#define C_TMU  2754   // 5202 : t_mu (2 per ij)          (identity + bias)
#define C_TVR  7956   // 7803 : per ij: d0=exp(clip), ofac=0.9*tanh(0.5*sum), d1=exp(clip)
#define NCOL   15759
#define NPAD   15872  // 124*128

__device__ __forceinline__ u16 f2bf(float f) {
  uint32_t u = __float_as_uint(f);
  u += 0x7fffu + ((u >> 16) & 1u);   // RNE
  return (u16)(u >> 16);
}
__device__ __forceinline__ float bf2f(u16 h) {
  return __uint_as_float((uint32_t)h << 16);
}
__device__ __forceinline__ float frcp(float x) { return __builtin_amdgcn_rcpf(x); }
__device__ __forceinline__ float flog(float x) { return __builtin_amdgcn_logf(x) * 0.6931471805599453f; }

// ---------------------------------------------------------------- build A
// A_cat[m][k'] bf16, k'<512: hi(x), 512..1023: lo(x), 1024..1535: hi(x)
__global__ __launch_bounds__(256) void build_a_kernel(const float* __restrict__ x,
                                                      u16* __restrict__ A) {
  int idx = blockIdx.x * 256 + threadIdx.x;   // exactly 4096*512
  int m = idx >> 9;
  int k = idx & 511;
  float v = x[idx];
  u16 h = f2bf(v);
  u16 l = f2bf(v - bf2f(h));
  u16* row = A + (size_t)m * KQ;
  row[k] = h;
  row[DQ + k] = l;
  row[2 * DQ + k] = h;
}

// ---------------------------------------------------------------- build B^T
// BT[n][k'] bf16 (n-major rows of K=1536): k'<512: Wh, 512..: Wh, 1024..: Wl
__global__ __launch_bounds__(256) void build_b_kernel(
    const float* __restrict__ Ws_w, const float* __restrict__ Ws_mu,
    const float* __restrict__ Ws_var, const float* __restrict__ Wt_w,
    const float* __restrict__ Wt_mu, const float* __restrict__ Wt_var,
    u16* __restrict__ BT) {
  int n = blockIdx.x * 256 + threadIdx.x;
  if (n >= NPAD) return;
  const float* src = Ws_w;
  int c0 = 0, stride = 51, two = 0, pad = 0;
  if (n >= NCOL) { pad = 1; }
  else if (n < C_SMU)  { src = Ws_w;   stride = 51;    c0 = n; }
  else if (n < C_SVAR) { src = Ws_mu;  stride = 51;    c0 = n - C_SMU; }
  else if (n < C_TW)   { src = Ws_var; stride = 51;    c0 = n - C_SVAR; }
  else if (n < C_TMU)  { src = Wt_w;   stride = 2601;  c0 = n - C_TW; }
  else if (n < C_TVR)  { src = Wt_mu;  stride = 5202;  c0 = n - C_TMU; }
  else {
    int np = n - C_TVR;
    int ij = (int)((unsigned)np / 3u);
    int r = np - ij * 3;
    src = Wt_var; stride = 10404;
    c0 = ij * 4 + (r == 0 ? 0 : (r == 1 ? 1 : 3));
    two = (r == 1);                         // sum of the two off-diagonal cols
  }
  u16* row = BT + (size_t)n * KQ;
  for (int kb = 0; kb < DQ; kb += 8) {
    union { u16 u[8]; uint4 v; } H, L;
#pragma unroll
    for (int t = 0; t < 8; ++t) {
      float w = 0.f;
      if (!pad) {
        const float* p = src + (size_t)(kb + t) * stride + c0;
        w = p[0];
        if (two) w += p[1];
      }
      u16 h = f2bf(w);
      H.u[t] = h;
      L.u[t] = f2bf(w - bf2f(h));
    }
    *(uint4*)(row + kb) = H.v;
    *(uint4*)(row + DQ + kb) = H.v;
    *(uint4*)(row + 2 * DQ + kb) = L.v;
  }
}

// ---------------------------------------------------------------- epilogue transform
__device__ __forceinline__ float xform(int n, float v,
    const float* __restrict__ bs_w, const float* __restrict__ bs_mu,
    const float* __restrict__ bs_var, const float* __restrict__ bt_w,
    const float* __restrict__ bt_mu, const float* __restrict__ bt_var) {
  if (n < C_TW) {
    if (n < C_SMU)  return v + bs_w[n];
    if (n < C_SVAR) return v + bs_mu[n - C_SMU];
    float u = v + bs_var[n - C_SVAR];
    u = fminf(fmaxf(u, -1.f), 1.f);
    return __expf(u);
  }
  if (n < C_TMU) return v + bt_w[n - C_TW];
  if (n < C_TVR) return v + bt_mu[n - C_TMU];
  int np = n - C_TVR;
  int ij = (int)((unsigned)np / 3u);
  int r = np - ij * 3;
  if (r == 1) {
    float u = v + bt_var[ij * 4 + 1] + bt_var[ij * 4 + 2];
    u = fminf(fmaxf(u, -20.f), 20.f);
    float ex = __expf(u);                 // tanh(u/2) = (e^u-1)/(e^u+1)
    return 0.9f * (ex - 1.f) / (ex + 1.f);
  }
  float u = v + bt_var[ij * 4 + (r == 0 ? 0 : 3)];
  u = fminf(fmaxf(u, -1.f), 1.f);
  return __expf(u);
}

// ---------------------------------------------------------------- GEMM (m97-style)
// C[mloc][n] = A[gr(mloc)][:] . BT[n][:],  128x128 tile, BK=64, 16x16x32 bf16 MFMA
__global__ __launch_bounds__(256, 2) void gemm_kernel(
    const u16* __restrict__ A, const u16* __restrict__ BT, float* __restrict__ C,
    const float* __restrict__ bs_w, const float* __restrict__ bs_mu,
    const float* __restrict__ bs_var, const float* __restrict__ bt_w,
    const float* __restrict__ bt_mu, const float* __restrict__ bt_var,
    int t0, int lgTC) {
  __shared__ uint4 sA[1024];   // 16B units: [kc(0..7)][row(0..127)]
  __shared__ uint4 sB[1024];   // 16B units: [kc(0..7)][n(0..127)]
  const int tid = threadIdx.x;
  const int lane = tid & 63;
  const int wave = tid >> 6;
  const int wm = (wave >> 1) * 64;
  const int wn = (wave & 1) * 64;
  const int q4 = lane >> 4;
  const int c16 = lane & 15;
  const int mtile = blockIdx.y;
  const int ntile = blockIdx.x;
  const int tcm1 = (1 << lgTC) - 1;

  uint32_t aoff[4], boff[4];
#pragma unroll
  for (int s = 0; s < 4; ++s) {
    int jj = wave * 4 + s;                     // staging instr 0..15
    int kc = jj >> 1;
    int r = ((jj & 1) << 6) + lane;            // tile row / tile col
    int mloc = mtile * 128 + r;
    int gr = ((mloc >> lgTC) << 8) + t0 + (mloc & tcm1);  // global x-row = b*256 + t
    aoff[s] = (uint32_t)gr * KQ + kc * 8;
    int n = ntile * 128 + r;
    boff[s] = (uint32_t)n * KQ + kc * 8;
  }

  f32x4 acc[4][4];
#pragma unroll
  for (int a_ = 0; a_ < 4; ++a_)
#pragma unroll
    for (int b_ = 0; b_ < 4; ++b_) acc[a_][b_] = (f32x4){0.f, 0.f, 0.f, 0.f};

  AS3 uint4* sA3 = (AS3 uint4*)sA;
  AS3 uint4* sB3 = (AS3 uint4*)sB;

  for (int k0 = 0; k0 < KQ; k0 += 64) {
#pragma unroll
    for (int s = 0; s < 4; ++s) {
      int jj = wave * 4 + s;
      __builtin_amdgcn_global_load_lds((const AS1 void*)(A + aoff[s] + k0),
                                       (AS3 void*)(sA3 + jj * 64), 16, 0, 0);
      __builtin_amdgcn_global_load_lds((const AS1 void*)(BT + boff[s] + k0),
                                       (AS3 void*)(sB3 + jj * 64), 16, 0, 0);
    }
    __syncthreads();
#pragma unroll
    for (int ks = 0; ks < 2; ++ks) {
      int kc = ks * 4 + q4;
      short8 af[4], bfv[4];
#pragma unroll
      for (int f = 0; f < 4; ++f) {
        af[f]  = *(const short8*)&sA[kc * 128 + wm + f * 16 + c16];
        bfv[f] = *(const short8*)&sB[kc * 128 + wn + f * 16 + c16];
      }
#pragma unroll
      for (int fr = 0; fr < 4; ++fr)
#pragma unroll
        for (int fc = 0; fc < 4; ++fc)
          acc[fr][fc] = __builtin_amdgcn_mfma_f32_16x16x32_bf16(af[fr], bfv[fc],
                                                                acc[fr][fc], 0, 0, 0);
    }
    __syncthreads();
  }

  // epilogue: C/D layout col=lane&15, row=q4*4+reg
#pragma unroll
  for (int fr = 0; fr < 4; ++fr) {
    int grow = mtile * 128 + wm + fr * 16 + q4 * 4;
#pragma unroll
    for (int fc = 0; fc < 4; ++fc) {
      int col = ntile * 128 + wn + fc * 16 + c16;
      if (col < NCOL) {
        float* cp = C + (size_t)grow * NPAD + col;
#pragma unroll
        for (int i = 0; i < 4; ++i) {
          float vv = xform(col, acc[fr][fc][i], bs_w, bs_mu, bs_var, bt_w, bt_mu, bt_var);
          cp[(size_t)i * NPAD] = vv;
        }
      }
    }
  }
}

// ---------------------------------------------------------------- scan
struct Vals { float sw, smu, svar, tw, m0, m1, d0, ofac, d1; };

__device__ __forceinline__ Vals ldvals(const float* __restrict__ r, int ij, int j) {
  Vals v;
  v.sw = r[C_SW + j]; v.smu = r[C_SMU + j]; v.svar = r[C_SVAR + j];
  v.tw = r[C_TW + ij];
  float2 mm = *(const float2*)(r + C_TMU + 2 * ij);
  v.m0 = mm.x; v.m1 = mm.y;
  const float* tv = r + C_TVR + 3 * ij;
  v.d0 = tv[0]; v.ofac = tv[1]; v.d1 = tv[2];
  return v;
}

template <bool CHILD>
__device__ __forceinline__ float merge2(const Vals& v, float nmu, float nvar,
                                        float& mu_n, float& var_n) {
  float off = v.ofac * __builtin_amdgcn_sqrtf(v.d0 * v.d1);
  float det = fmaf(v.d0, v.d1, -off * off);
  float inv = frcp(det);
  float a = v.d1 * inv, bo = -off * inv, d = v.d0 * inv;
  float e0 = a * v.m0 + bo * v.m1;
  float e1 = bo * v.m0 + d * v.m1;
  float quad1 = e0 * e0 * v.d0 + 2.f * e0 * e1 * off + e1 * e1 * v.d1;
  float zeta1 = -0.5f * (2.f * LOG2PI_F + flog(det) + quad1);
  float l2 = frcp(nvar);
  float eta2 = nmu * l2;
  float zeta2 = -0.5f * (LOG2PI_F + flog(nvar) + nmu * eta2);
  float den, keep, es, la;
  if (CHILD) { den = d + l2; keep = e0; es = e1 + eta2; }
  else       { den = a + l2; keep = e1; es = e0 + eta2; }
  float rden = frcp(den);
  if (CHILD) la = a - bo * bo * rden;
  else       la = d - bo * bo * rden;
  float etan = keep - bo * rden * es;
  var_n = frcp(la);
  mu_n = var_n * etan;
  float zm = -0.5f * (LOG2PI_F - flog(den) + es * es * rden);
  float zn = -0.5f * (LOG2PI_F - flog(la) + etan * etan * var_n);
  return zeta1 + zeta2 - zm - zn;
}

__global__ __launch_bounds__(256) void scan_kernel(
    const float* __restrict__ Cws, float* __restrict__ out, float* __restrict__ carry,
    int t0, int TC, int isFirst, int isLast) {
  int ij = blockIdx.y * 256 + threadIdx.x;
  if (ij >= L2Q) return;
  int b = blockIdx.x;
  int j = ij % 51;
  const float* base = Cws + (size_t)b * TC * NPAD;  // chunk-local rows
  float mu_p, var_p;
  Vals cur;
  int tstart;
  if (isFirst) {
    Vals v0 = ldvals(base, ij, j);
    float mu_c, var_c;
    float sc0 = merge2<true>(v0, v0.smu, v0.svar, mu_c, var_c);
    Vals v1 = ldvals(base + NPAD, ij, j);
    float sp0 = merge2<false>(v1, mu_c, var_c, mu_p, var_p);
    out[(size_t)(b * TQ + 0) * L2Q + ij] = sc0 + sp0 + v0.tw + v0.sw;
    cur = v1;
    tstart = 1;
  } else {
    mu_p = carry[b * L2Q + ij];
    var_p = carry[BQ * L2Q + b * L2Q + ij];
    cur = ldvals(base, ij, j);
    tstart = t0;
  }
  int tend = t0 + TC;
  for (int t = tstart; t < tend; ++t) {
    Vals nxt = cur;
    if (t + 1 < tend) nxt = ldvals(base + (size_t)(t + 1 - t0) * NPAD, ij, j);  // prefetch
    float vsum = var_p + cur.svar;
    float rv = frcp(vsum);
    float logv = flog(vsum);
    float dmu = mu_p - cur.smu;
    float sc = -0.5f * (LOG2PI_F + logv + dmu * dmu * rv);
    float mu_c = (mu_p * cur.svar + cur.smu * var_p) * rv;
    float var_c = vsum - 0.5f * logv;
    float sp = merge2<false>(cur, mu_c, var_c, mu_p, var_p);
    out[(size_t)(b * TQ + t) * L2Q + ij] = sc + sp + cur.tw + cur.sw;
    cur = nxt;
  }
  if (!isLast) {
    carry[b * L2Q + ij] = mu_p;
    carry[BQ * L2Q + b * L2Q + ij] = var_p;
  }
}

// ---------------------------------------------------------------- launch
extern "C" void kernel_launch(void* const* d_in, const int* in_sizes, int n_in,
                              void* d_out, int out_size, void* d_ws, size_t ws_size,
                              hipStream_t stream) {
  (void)in_sizes; (void)n_in; (void)out_size;
  const float* x      = (const float*)d_in[0];
  const float* Ws_w   = (const float*)d_in[1];
  const float* bs_w   = (const float*)d_in[2];
  const float* Ws_mu  = (const float*)d_in[3];
  const float* bs_mu  = (const float*)d_in[4];
  const float* Ws_var = (const float*)d_in[5];
  const float* bs_var = (const float*)d_in[6];
  const float* Wt_w   = (const float*)d_in[7];
  const float* bt_w   = (const float*)d_in[8];
  const float* Wt_mu  = (const float*)d_in[9];
  const float* bt_mu  = (const float*)d_in[10];
  const float* Wt_var = (const float*)d_in[11];
  const float* bt_var = (const float*)d_in[12];
  float* out = (float*)d_out;

  char* ws = (char*)d_ws;
  const size_t szA = (size_t)4096 * KQ * 2;          // 12,582,912 (256-aligned)
  const size_t szB = (size_t)NPAD * KQ * 2;          // 48,758,784 (256-aligned)
  const size_t szCar = ((size_t)BQ * L2Q * 2 * 4 + 255) & ~(size_t)255;
  u16* Abf = (u16*)ws;
  u16* BTb = (u16*)(ws + szA);
  float* carry = (float*)(ws + szA + szB);
  size_t offC = szA + szB + szCar;
  float* Cws = (float*)(ws + offC);

  // chunk T so the phase-1 buffer fits in ws
  int TC = 256;
  while (TC > 8 && offC + (size_t)BQ * TC * NPAD * 4 > ws_size) TC >>= 1;
  int lgTC = 31 - __builtin_clz((unsigned)TC);
  int nch = TQ / TC;

  build_a_kernel<<<dim3((4096 * 512) / 256), dim3(256), 0, stream>>>(x, Abf);
  build_b_kernel<<<dim3(NPAD / 256), dim3(256), 0, stream>>>(Ws_w, Ws_mu, Ws_var,
                                                             Wt_w, Wt_mu, Wt_var, BTb);
  for (int c = 0; c < nch; ++c) {
    int t0 = c * TC;
    gemm_kernel<<<dim3(NPAD / 128, (BQ * TC) / 128), dim3(256), 0, stream>>>(
        Abf, BTb, Cws, bs_w, bs_mu, bs_var, bt_w, bt_mu, bt_var, t0, lgTC);
    scan_kernel<<<dim3(BQ, (L2Q + 255) / 256), dim3(256), 0, stream>>>(
        Cws, out, carry, t0, TC, c == 0 ? 1 : 0, c == nch - 1 ? 1 : 0);
  }
}

// Round 2
// 1067.644 us; speedup vs baseline: 1.0304x; 1.0304x over previous
//
#include <hip/hip_runtime.h>
#include <stdint.h>

#define AS1 __attribute__((address_space(1)))
#define AS3 __attribute__((address_space(3)))

typedef unsigned short u16;
typedef __attribute__((ext_vector_type(8))) short short8;
typedef __attribute__((ext_vector_type(4))) float f32x4;

#define LOG2PI_F 1.8378770664093453f

// problem constants
#define BQ   16
#define TQ   256
#define DQ   512
#define LQ   51
#define L2Q  2601
#define KQ   1536     // 3*512 (split-bf16: [xh, xl, xh] . [Wh; Wh; Wl])
// column layout of the fused projection (per (b,t) row)
#define C_SW   0      // 51   : s_w                      (identity + bias)
#define C_SMU  51     // 51   : s_mu                     (identity + bias)
#define C_SVAR 102    // 51   : s_var = exp(clip(.))
#define C_TW   153    // 2601 : t_w                      (identity + bias)
#define C_TMU  2754   // 5202 : t_mu (2 per ij)          (identity + bias)
#define C_TVR  7956   // 7803 : per ij: d0=exp(clip), ofac=0.9*tanh(0.5*sum), d1=exp(clip)
#define NCOL   15759
#define NPAD   15872  // 124*128

__device__ __forceinline__ u16 f2bf(float f) {
  uint32_t u = __float_as_uint(f);
  u += 0x7fffu + ((u >> 16) & 1u);   // RNE
  return (u16)(u >> 16);
}
__device__ __forceinline__ float bf2f(u16 h) {
  return __uint_as_float((uint32_t)h << 16);
}
__device__ __forceinline__ float frcp(float x) { return __builtin_amdgcn_rcpf(x); }
__device__ __forceinline__ float flog(float x) { return __builtin_amdgcn_logf(x) * 0.6931471805599453f; }

// ---------------------------------------------------------------- build A
__global__ __launch_bounds__(256) void build_a_kernel(const float* __restrict__ x,
                                                      u16* __restrict__ A) {
  int idx = blockIdx.x * 256 + threadIdx.x;   // exactly 4096*512
  int m = idx >> 9;
  int k = idx & 511;
  float v = x[idx];
  u16 h = f2bf(v);
  u16 l = f2bf(v - bf2f(h));
  u16* row = A + (size_t)m * KQ;
  row[k] = h;
  row[DQ + k] = l;
  row[2 * DQ + k] = h;
}

// ---------------------------------------------------------------- build B^T
__global__ __launch_bounds__(256) void build_b_kernel(
    const float* __restrict__ Ws_w, const float* __restrict__ Ws_mu,
    const float* __restrict__ Ws_var, const float* __restrict__ Wt_w,
    const float* __restrict__ Wt_mu, const float* __restrict__ Wt_var,
    u16* __restrict__ BT) {
  int n = blockIdx.x * 256 + threadIdx.x;
  if (n >= NPAD) return;
  const float* src = Ws_w;
  int c0 = 0, stride = 51, two = 0, pad = 0;
  if (n >= NCOL) { pad = 1; }
  else if (n < C_SMU)  { src = Ws_w;   stride = 51;    c0 = n; }
  else if (n < C_SVAR) { src = Ws_mu;  stride = 51;    c0 = n - C_SMU; }
  else if (n < C_TW)   { src = Ws_var; stride = 51;    c0 = n - C_SVAR; }
  else if (n < C_TMU)  { src = Wt_w;   stride = 2601;  c0 = n - C_TW; }
  else if (n < C_TVR)  { src = Wt_mu;  stride = 5202;  c0 = n - C_TMU; }
  else {
    int np = n - C_TVR;
    int ij = (int)((unsigned)np / 3u);
    int r = np - ij * 3;
    src = Wt_var; stride = 10404;
    c0 = ij * 4 + (r == 0 ? 0 : (r == 1 ? 1 : 3));
    two = (r == 1);                         // sum of the two off-diagonal cols
  }
  u16* row = BT + (size_t)n * KQ;
  for (int kb = 0; kb < DQ; kb += 8) {
    union { u16 u[8]; uint4 v; } H, L;
#pragma unroll
    for (int t = 0; t < 8; ++t) {
      float w = 0.f;
      if (!pad) {
        const float* p = src + (size_t)(kb + t) * stride + c0;
        w = p[0];
        if (two) w += p[1];
      }
      u16 h = f2bf(w);
      H.u[t] = h;
      L.u[t] = f2bf(w - bf2f(h));
    }
    *(uint4*)(row + kb) = H.v;
    *(uint4*)(row + DQ + kb) = H.v;
    *(uint4*)(row + 2 * DQ + kb) = L.v;
  }
}

// ---------------------------------------------------------------- epilogue transform
__device__ __forceinline__ float xform(int n, float v,
    const float* __restrict__ bs_w, const float* __restrict__ bs_mu,
    const float* __restrict__ bs_var, const float* __restrict__ bt_w,
    const float* __restrict__ bt_mu, const float* __restrict__ bt_var) {
  if (n < C_TW) {
    if (n < C_SMU)  return v + bs_w[n];
    if (n < C_SVAR) return v + bs_mu[n - C_SMU];
    float u = v + bs_var[n - C_SVAR];
    u = fminf(fmaxf(u, -1.f), 1.f);
    return __expf(u);
  }
  if (n < C_TMU) return v + bt_w[n - C_TW];
  if (n < C_TVR) return v + bt_mu[n - C_TMU];
  int np = n - C_TVR;
  int ij = (int)((unsigned)np / 3u);
  int r = np - ij * 3;
  if (r == 1) {
    float u = v + bt_var[ij * 4 + 1] + bt_var[ij * 4 + 2];
    u = fminf(fmaxf(u, -20.f), 20.f);
    float ex = __expf(u);                 // tanh(u/2) = (e^u-1)/(e^u+1)
    return 0.9f * (ex - 1.f) / (ex + 1.f);
  }
  float u = v + bt_var[ij * 4 + (r == 0 ? 0 : 3)];
  u = fminf(fmaxf(u, -1.f), 1.f);
  return __expf(u);
}

// ---------------------------------------------------------------- GEMM (m97-style)
// mtile on blockIdx.x (16 per chunk): consecutive blocks share one ntile's
// 393KB B-slice (L2-hot) while whole 6.3MB A-chunk is shared by all cohorts.
__global__ __launch_bounds__(256, 2) void gemm_kernel(
    const u16* __restrict__ A, const u16* __restrict__ BT, float* __restrict__ C,
    const float* __restrict__ bs_w, const float* __restrict__ bs_mu,
    const float* __restrict__ bs_var, const float* __restrict__ bt_w,
    const float* __restrict__ bt_mu, const float* __restrict__ bt_var,
    int t0, int lgTC) {
  __shared__ uint4 sA[1024];   // 16B units: [kc(0..7)][row(0..127)]
  __shared__ uint4 sB[1024];   // 16B units: [kc(0..7)][n(0..127)]
  const int tid = threadIdx.x;
  const int lane = tid & 63;
  const int wave = tid >> 6;
  const int wm = (wave >> 1) * 64;
  const int wn = (wave & 1) * 64;
  const int q4 = lane >> 4;
  const int c16 = lane & 15;
  const int mtile = blockIdx.x;
  const int ntile = blockIdx.y;
  const int tcm1 = (1 << lgTC) - 1;

  uint32_t aoff[4], boff[4];
#pragma unroll
  for (int s = 0; s < 4; ++s) {
    int jj = wave * 4 + s;                     // staging instr 0..15
    int kc = jj >> 1;
    int r = ((jj & 1) << 6) + lane;            // tile row / tile col
    int mloc = mtile * 128 + r;
    int gr = ((mloc >> lgTC) << 8) + t0 + (mloc & tcm1);  // global x-row = b*256 + t
    aoff[s] = (uint32_t)gr * KQ + kc * 8;
    int n = ntile * 128 + r;
    boff[s] = (uint32_t)n * KQ + kc * 8;
  }

  f32x4 acc[4][4];
#pragma unroll
  for (int a_ = 0; a_ < 4; ++a_)
#pragma unroll
    for (int b_ = 0; b_ < 4; ++b_) acc[a_][b_] = (f32x4){0.f, 0.f, 0.f, 0.f};

  AS3 uint4* sA3 = (AS3 uint4*)sA;
  AS3 uint4* sB3 = (AS3 uint4*)sB;

  for (int k0 = 0; k0 < KQ; k0 += 64) {
#pragma unroll
    for (int s = 0; s < 4; ++s) {
      int jj = wave * 4 + s;
      __builtin_amdgcn_global_load_lds((const AS1 void*)(A + aoff[s] + k0),
                                       (AS3 void*)(sA3 + jj * 64), 16, 0, 0);
      __builtin_amdgcn_global_load_lds((const AS1 void*)(BT + boff[s] + k0),
                                       (AS3 void*)(sB3 + jj * 64), 16, 0, 0);
    }
    __syncthreads();
#pragma unroll
    for (int ks = 0; ks < 2; ++ks) {
      int kc = ks * 4 + q4;
      short8 af[4], bfv[4];
#pragma unroll
      for (int f = 0; f < 4; ++f) {
        af[f]  = *(const short8*)&sA[kc * 128 + wm + f * 16 + c16];
        bfv[f] = *(const short8*)&sB[kc * 128 + wn + f * 16 + c16];
      }
#pragma unroll
      for (int fr = 0; fr < 4; ++fr)
#pragma unroll
        for (int fc = 0; fc < 4; ++fc)
          acc[fr][fc] = __builtin_amdgcn_mfma_f32_16x16x32_bf16(af[fr], bfv[fc],
                                                                acc[fr][fc], 0, 0, 0);
    }
    __syncthreads();
  }

  // epilogue: C/D layout col=lane&15, row=q4*4+reg
#pragma unroll
  for (int fr = 0; fr < 4; ++fr) {
    int grow = mtile * 128 + wm + fr * 16 + q4 * 4;
#pragma unroll
    for (int fc = 0; fc < 4; ++fc) {
      int col = ntile * 128 + wn + fc * 16 + c16;
      if (col < NCOL) {
        float* cp = C + (size_t)grow * NPAD + col;
#pragma unroll
        for (int i = 0; i < 4; ++i) {
          float vv = xform(col, acc[fr][fc][i], bs_w, bs_mu, bs_var, bt_w, bt_mu, bt_var);
          cp[(size_t)i * NPAD] = vv;
        }
      }
    }
  }
}

// ---------------------------------------------------------------- scan
struct Vals { float sw, smu, svar, tw, m0, m1, d0, ofac, d1; };

__device__ __forceinline__ Vals ldvals(const float* __restrict__ r, int ij, int j) {
  Vals v;
  v.sw = r[C_SW + j]; v.smu = r[C_SMU + j]; v.svar = r[C_SVAR + j];
  v.tw = r[C_TW + ij];
  float2 mm = *(const float2*)(r + C_TMU + 2 * ij);
  v.m0 = mm.x; v.m1 = mm.y;
  const float* tv = r + C_TVR + 3 * ij;
  v.d0 = tv[0]; v.ofac = tv[1]; v.d1 = tv[2];
  return v;
}

template <bool CHILD>
__device__ __forceinline__ float merge2(const Vals& v, float nmu, float nvar,
                                        float& mu_n, float& var_n) {
  float off = v.ofac * __builtin_amdgcn_sqrtf(v.d0 * v.d1);
  float det = fmaf(v.d0, v.d1, -off * off);
  float inv = frcp(det);
  float a = v.d1 * inv, bo = -off * inv, d = v.d0 * inv;
  float e0 = a * v.m0 + bo * v.m1;
  float e1 = bo * v.m0 + d * v.m1;
  float quad1 = e0 * e0 * v.d0 + 2.f * e0 * e1 * off + e1 * e1 * v.d1;
  float zeta1 = -0.5f * (2.f * LOG2PI_F + flog(det) + quad1);
  float l2 = frcp(nvar);
  float eta2 = nmu * l2;
  float zeta2 = -0.5f * (LOG2PI_F + flog(nvar) + nmu * eta2);
  float den, keep, es, la;
  if (CHILD) { den = d + l2; keep = e0; es = e1 + eta2; }
  else       { den = a + l2; keep = e1; es = e0 + eta2; }
  float rden = frcp(den);
  if (CHILD) la = a - bo * bo * rden;
  else       la = d - bo * bo * rden;
  float etan = keep - bo * rden * es;
  var_n = frcp(la);
  mu_n = var_n * etan;
  float zm = -0.5f * (LOG2PI_F - flog(den) + es * es * rden);
  float zn = -0.5f * (LOG2PI_F - flog(la) + etan * etan * var_n);
  return zeta1 + zeta2 - zm - zn;
}

#define PF 4   // prefetch ring depth: ~24 outstanding loads/lane

__global__ __launch_bounds__(256) void scan_kernel(
    const float* __restrict__ Cws, float* __restrict__ out, float* __restrict__ carry,
    int t0, int TC, int isFirst, int isLast) {
  int ij = blockIdx.y * 256 + threadIdx.x;
  if (ij >= L2Q) return;
  int b = blockIdx.x;
  int j = ij % 51;
  const float* base = Cws + (size_t)b * TC * NPAD;  // chunk-local rows
  float mu_p, var_p;
  int tstart;
  Vals ring[PF];
  if (isFirst) {
    Vals v0 = ldvals(base, ij, j);
    Vals v1 = ldvals(base + NPAD, ij, j);
    float mu_c, var_c;
    float sc0 = merge2<true>(v0, v0.smu, v0.svar, mu_c, var_c);
    float sp0 = merge2<false>(v1, mu_c, var_c, mu_p, var_p);
    out[(size_t)(b * TQ + 0) * L2Q + ij] = sc0 + sp0 + v0.tw + v0.sw;
    tstart = 1;
    ring[1 & (PF - 1)] = v1;
  } else {
    mu_p = carry[b * L2Q + ij];
    var_p = carry[BQ * L2Q + b * L2Q + ij];
    tstart = t0;
    ring[t0 & (PF - 1)] = ldvals(base, ij, j);
  }
  int tend = t0 + TC;
#pragma unroll
  for (int p = 1; p < PF; ++p) {
    int t = tstart + p;
    if (t < tend) ring[t & (PF - 1)] = ldvals(base + (size_t)(t - t0) * NPAD, ij, j);
  }
#pragma unroll 4
  for (int t = tstart; t < tend; ++t) {
    Vals cur = ring[t & (PF - 1)];
    int tp = t + PF;
    if (tp < tend) ring[tp & (PF - 1)] = ldvals(base + (size_t)(tp - t0) * NPAD, ij, j);
    float vsum = var_p + cur.svar;
    float rv = frcp(vsum);
    float logv = flog(vsum);
    float dmu = mu_p - cur.smu;
    float sc = -0.5f * (LOG2PI_F + logv + dmu * dmu * rv);
    float mu_c = (mu_p * cur.svar + cur.smu * var_p) * rv;
    float var_c = vsum - 0.5f * logv;
    float sp = merge2<false>(cur, mu_c, var_c, mu_p, var_p);
    out[(size_t)(b * TQ + t) * L2Q + ij] = sc + sp + cur.tw + cur.sw;
  }
  if (!isLast) {
    carry[b * L2Q + ij] = mu_p;
    carry[BQ * L2Q + b * L2Q + ij] = var_p;
  }
}

// ---------------------------------------------------------------- launch
extern "C" void kernel_launch(void* const* d_in, const int* in_sizes, int n_in,
                              void* d_out, int out_size, void* d_ws, size_t ws_size,
                              hipStream_t stream) {
  (void)in_sizes; (void)n_in; (void)out_size;
  const float* x      = (const float*)d_in[0];
  const float* Ws_w   = (const float*)d_in[1];
  const float* bs_w   = (const float*)d_in[2];
  const float* Ws_mu  = (const float*)d_in[3];
  const float* bs_mu  = (const float*)d_in[4];
  const float* Ws_var = (const float*)d_in[5];
  const float* bs_var = (const float*)d_in[6];
  const float* Wt_w   = (const float*)d_in[7];
  const float* bt_w   = (const float*)d_in[8];
  const float* Wt_mu  = (const float*)d_in[9];
  const float* bt_mu  = (const float*)d_in[10];
  const float* Wt_var = (const float*)d_in[11];
  const float* bt_var = (const float*)d_in[12];
  float* out = (float*)d_out;

  char* ws = (char*)d_ws;
  const size_t szA = (size_t)4096 * KQ * 2;          // 12,582,912 (256-aligned)
  const size_t szB = (size_t)NPAD * KQ * 2;          // 48,758,784 (256-aligned)
  const size_t szCar = ((size_t)BQ * L2Q * 2 * 4 + 255) & ~(size_t)255;
  u16* Abf = (u16*)ws;
  u16* BTb = (u16*)(ws + szA);
  float* carry = (float*)(ws + szA + szB);
  size_t offC = szA + szB + szCar;
  float* Cws = (float*)(ws + offC);

  // chunk T so the phase-1 buffer fits in ws
  int TC = 256;
  while (TC > 8 && offC + (size_t)BQ * TC * NPAD * 4 > ws_size) TC >>= 1;
  int lgTC = 31 - __builtin_clz((unsigned)TC);
  int nch = TQ / TC;

  build_a_kernel<<<dim3((4096 * 512) / 256), dim3(256), 0, stream>>>(x, Abf);
  build_b_kernel<<<dim3(NPAD / 256), dim3(256), 0, stream>>>(Ws_w, Ws_mu, Ws_var,
                                                             Wt_w, Wt_mu, Wt_var, BTb);
  for (int c = 0; c < nch; ++c) {
    int t0 = c * TC;
    gemm_kernel<<<dim3((BQ * TC) / 128, NPAD / 128), dim3(256), 0, stream>>>(
        Abf, BTb, Cws, bs_w, bs_mu, bs_var, bt_w, bt_mu, bt_var, t0, lgTC);
    scan_kernel<<<dim3(BQ, (L2Q + 255) / 256), dim3(256), 0, stream>>>(
        Cws, out, carry, t0, TC, c == 0 ? 1 : 0, c == nch - 1 ? 1 : 0);
  }
}

// Round 3
// 862.304 us; speedup vs baseline: 1.2758x; 1.2381x over previous
//
#include <hip/hip_runtime.h>
#include <stdint.h>

#define AS1 __attribute__((address_space(1)))
#define AS3 __attribute__((address_space(3)))

typedef unsigned short u16;
typedef __attribute__((ext_vector_type(8))) short short8;
typedef __attribute__((ext_vector_type(4))) float f32x4;

#define LOG2PI_F 1.8378770664093453f

// problem constants
#define BQ   16
#define TQ   256
#define DQ   512
#define LQ   51
#define L2Q  2601
#define KQ   1536     // 3*512 (split-bf16: [xh, xl, xh] . [Wh; Wh; Wl])
// column layout of the fused projection (per (b,t) row)
#define C_SW   0      // 51   : s_w                      (identity + bias)
#define C_SMU  51     // 51   : s_mu                     (identity + bias)
#define C_SVAR 102    // 51   : s_var = exp(clip(.))
#define C_TW   153    // 2601 : t_w                      (identity + bias)
#define C_TMU  2754   // 5202 : t_mu (2 per ij)          (identity + bias)
#define C_TVR  7956   // 7803 : per ij: d0=exp(clip), ofac=0.9*tanh(0.5*sum), d1=exp(clip)
#define NCOL   15759
#define NPAD   15872  // 124*128

__device__ __forceinline__ u16 f2bf(float f) {
  uint32_t u = __float_as_uint(f);
  u += 0x7fffu + ((u >> 16) & 1u);   // RNE
  return (u16)(u >> 16);
}
__device__ __forceinline__ float bf2f(u16 h) {
  return __uint_as_float((uint32_t)h << 16);
}
__device__ __forceinline__ float frcp(float x) { return __builtin_amdgcn_rcpf(x); }
__device__ __forceinline__ float flog(float x) { return __builtin_amdgcn_logf(x) * 0.6931471805599453f; }

// ---------------------------------------------------------------- build A
__global__ __launch_bounds__(256) void build_a_kernel(const float* __restrict__ x,
                                                      u16* __restrict__ A) {
  int idx = blockIdx.x * 256 + threadIdx.x;   // exactly 4096*512
  int m = idx >> 9;
  int k = idx & 511;
  float v = x[idx];
  u16 h = f2bf(v);
  u16 l = f2bf(v - bf2f(h));
  u16* row = A + (size_t)m * KQ;
  row[k] = h;
  row[DQ + k] = l;
  row[2 * DQ + k] = h;
}

// ---------------------------------------------------------------- build B^T
// k-parallel: blockIdx.y picks an 8-wide k-slab (64 slabs), thread = column n.
// Loads for a fixed k are coalesced across consecutive n (W is k-major).
__global__ __launch_bounds__(256) void build_b_kernel(
    const float* __restrict__ Ws_w, const float* __restrict__ Ws_mu,
    const float* __restrict__ Ws_var, const float* __restrict__ Wt_w,
    const float* __restrict__ Wt_mu, const float* __restrict__ Wt_var,
    u16* __restrict__ BT) {
  int n = blockIdx.x * 256 + threadIdx.x;
  if (n >= NPAD) return;
  const float* src = Ws_w;
  int c0 = 0, stride = 51, two = 0, pad = 0;
  if (n >= NCOL) { pad = 1; }
  else if (n < C_SMU)  { src = Ws_w;   stride = 51;    c0 = n; }
  else if (n < C_SVAR) { src = Ws_mu;  stride = 51;    c0 = n - C_SMU; }
  else if (n < C_TW)   { src = Ws_var; stride = 51;    c0 = n - C_SVAR; }
  else if (n < C_TMU)  { src = Wt_w;   stride = 2601;  c0 = n - C_TW; }
  else if (n < C_TVR)  { src = Wt_mu;  stride = 5202;  c0 = n - C_TMU; }
  else {
    int np = n - C_TVR;
    int ij = (int)((unsigned)np / 3u);
    int r = np - ij * 3;
    src = Wt_var; stride = 10404;
    c0 = ij * 4 + (r == 0 ? 0 : (r == 1 ? 1 : 3));
    two = (r == 1);                         // sum of the two off-diagonal cols
  }
  u16* row = BT + (size_t)n * KQ;
  int kb = blockIdx.y * 8;
  union { u16 u[8]; uint4 v; } H, L;
#pragma unroll
  for (int t = 0; t < 8; ++t) {
    float w = 0.f;
    if (!pad) {
      const float* p = src + (size_t)(kb + t) * stride + c0;
      w = p[0];
      if (two) w += p[1];
    }
    u16 h = f2bf(w);
    H.u[t] = h;
    L.u[t] = f2bf(w - bf2f(h));
  }
  *(uint4*)(row + kb) = H.v;
  *(uint4*)(row + DQ + kb) = H.v;
  *(uint4*)(row + 2 * DQ + kb) = L.v;
}

// ---------------------------------------------------------------- epilogue transform
__device__ __forceinline__ float xform(int n, float v,
    const float* __restrict__ bs_w, const float* __restrict__ bs_mu,
    const float* __restrict__ bs_var, const float* __restrict__ bt_w,
    const float* __restrict__ bt_mu, const float* __restrict__ bt_var) {
  if (n < C_TW) {
    if (n < C_SMU)  return v + bs_w[n];
    if (n < C_SVAR) return v + bs_mu[n - C_SMU];
    float u = v + bs_var[n - C_SVAR];
    u = fminf(fmaxf(u, -1.f), 1.f);
    return __expf(u);
  }
  if (n < C_TMU) return v + bt_w[n - C_TW];
  if (n < C_TVR) return v + bt_mu[n - C_TMU];
  int np = n - C_TVR;
  int ij = (int)((unsigned)np / 3u);
  int r = np - ij * 3;
  if (r == 1) {
    float u = v + bt_var[ij * 4 + 1] + bt_var[ij * 4 + 2];
    u = fminf(fmaxf(u, -20.f), 20.f);
    float ex = __expf(u);                 // tanh(u/2) = (e^u-1)/(e^u+1)
    return 0.9f * (ex - 1.f) / (ex + 1.f);
  }
  float u = v + bt_var[ij * 4 + (r == 0 ? 0 : 3)];
  u = fminf(fmaxf(u, -1.f), 1.f);
  return __expf(u);
}

// ---------------------------------------------------------------- GEMM (m97-style)
// mtile on blockIdx.x (16 per chunk): consecutive blocks share one ntile's
// 393KB B-slice (L2-hot) while whole 6.3MB A-chunk is shared by all cohorts.
__global__ __launch_bounds__(256, 2) void gemm_kernel(
    const u16* __restrict__ A, const u16* __restrict__ BT, float* __restrict__ C,
    const float* __restrict__ bs_w, const float* __restrict__ bs_mu,
    const float* __restrict__ bs_var, const float* __restrict__ bt_w,
    const float* __restrict__ bt_mu, const float* __restrict__ bt_var,
    int t0, int lgTC) {
  __shared__ uint4 sA[1024];   // 16B units: [kc(0..7)][row(0..127)]
  __shared__ uint4 sB[1024];   // 16B units: [kc(0..7)][n(0..127)]
  const int tid = threadIdx.x;
  const int lane = tid & 63;
  const int wave = tid >> 6;
  const int wm = (wave >> 1) * 64;
  const int wn = (wave & 1) * 64;
  const int q4 = lane >> 4;
  const int c16 = lane & 15;
  const int mtile = blockIdx.x;
  const int ntile = blockIdx.y;
  const int tcm1 = (1 << lgTC) - 1;

  uint32_t aoff[4], boff[4];
#pragma unroll
  for (int s = 0; s < 4; ++s) {
    int jj = wave * 4 + s;                     // staging instr 0..15
    int kc = jj >> 1;
    int r = ((jj & 1) << 6) + lane;            // tile row / tile col
    int mloc = mtile * 128 + r;
    int gr = ((mloc >> lgTC) << 8) + t0 + (mloc & tcm1);  // global x-row = b*256 + t
    aoff[s] = (uint32_t)gr * KQ + kc * 8;
    int n = ntile * 128 + r;
    boff[s] = (uint32_t)n * KQ + kc * 8;
  }

  f32x4 acc[4][4];
#pragma unroll
  for (int a_ = 0; a_ < 4; ++a_)
#pragma unroll
    for (int b_ = 0; b_ < 4; ++b_) acc[a_][b_] = (f32x4){0.f, 0.f, 0.f, 0.f};

  AS3 uint4* sA3 = (AS3 uint4*)sA;
  AS3 uint4* sB3 = (AS3 uint4*)sB;

  for (int k0 = 0; k0 < KQ; k0 += 64) {
#pragma unroll
    for (int s = 0; s < 4; ++s) {
      int jj = wave * 4 + s;
      __builtin_amdgcn_global_load_lds((const AS1 void*)(A + aoff[s] + k0),
                                       (AS3 void*)(sA3 + jj * 64), 16, 0, 0);
      __builtin_amdgcn_global_load_lds((const AS1 void*)(BT + boff[s] + k0),
                                       (AS3 void*)(sB3 + jj * 64), 16, 0, 0);
    }
    __syncthreads();
#pragma unroll
    for (int ks = 0; ks < 2; ++ks) {
      int kc = ks * 4 + q4;
      short8 af[4], bfv[4];
#pragma unroll
      for (int f = 0; f < 4; ++f) {
        af[f]  = *(const short8*)&sA[kc * 128 + wm + f * 16 + c16];
        bfv[f] = *(const short8*)&sB[kc * 128 + wn + f * 16 + c16];
      }
#pragma unroll
      for (int fr = 0; fr < 4; ++fr)
#pragma unroll
        for (int fc = 0; fc < 4; ++fc)
          acc[fr][fc] = __builtin_amdgcn_mfma_f32_16x16x32_bf16(af[fr], bfv[fc],
                                                                acc[fr][fc], 0, 0, 0);
    }
    __syncthreads();
  }

  // epilogue: C/D layout col=lane&15, row=q4*4+reg
#pragma unroll
  for (int fr = 0; fr < 4; ++fr) {
    int grow = mtile * 128 + wm + fr * 16 + q4 * 4;
#pragma unroll
    for (int fc = 0; fc < 4; ++fc) {
      int col = ntile * 128 + wn + fc * 16 + c16;
      if (col < NCOL) {
        float* cp = C + (size_t)grow * NPAD + col;
#pragma unroll
        for (int i = 0; i < 4; ++i) {
          float vv = xform(col, acc[fr][fc][i], bs_w, bs_mu, bs_var, bt_w, bt_mu, bt_var);
          cp[(size_t)i * NPAD] = vv;
        }
      }
    }
  }
}

// ---------------------------------------------------------------- scan
struct Vals { float sw, smu, svar, tw, m0, m1, d0, ofac, d1; };

__device__ __forceinline__ Vals ldvals(const float* __restrict__ r, int ij, int j) {
  Vals v;
  v.sw = r[C_SW + j]; v.smu = r[C_SMU + j]; v.svar = r[C_SVAR + j];
  v.tw = r[C_TW + ij];
  float2 mm = *(const float2*)(r + C_TMU + 2 * ij);
  v.m0 = mm.x; v.m1 = mm.y;
  const float* tv = r + C_TVR + 3 * ij;
  v.d0 = tv[0]; v.ofac = tv[1]; v.d1 = tv[2];
  return v;
}

template <bool CHILD>
__device__ __forceinline__ float merge2(const Vals& v, float nmu, float nvar,
                                        float& mu_n, float& var_n) {
  float off = v.ofac * __builtin_amdgcn_sqrtf(v.d0 * v.d1);
  float det = fmaf(v.d0, v.d1, -off * off);
  float inv = frcp(det);
  float a = v.d1 * inv, bo = -off * inv, d = v.d0 * inv;
  float e0 = a * v.m0 + bo * v.m1;
  float e1 = bo * v.m0 + d * v.m1;
  float quad1 = e0 * e0 * v.d0 + 2.f * e0 * e1 * off + e1 * e1 * v.d1;
  float zeta1 = -0.5f * (2.f * LOG2PI_F + flog(det) + quad1);
  float l2 = frcp(nvar);
  float eta2 = nmu * l2;
  float zeta2 = -0.5f * (LOG2PI_F + flog(nvar) + nmu * eta2);
  float den, keep, es, la;
  if (CHILD) { den = d + l2; keep = e0; es = e1 + eta2; }
  else       { den = a + l2; keep = e1; es = e0 + eta2; }
  float rden = frcp(den);
  if (CHILD) la = a - bo * bo * rden;
  else       la = d - bo * bo * rden;
  float etan = keep - bo * rden * es;
  var_n = frcp(la);
  mu_n = var_n * etan;
  float zm = -0.5f * (LOG2PI_F - flog(den) + es * es * rden);
  float zn = -0.5f * (LOG2PI_F - flog(la) + etan * etan * var_n);
  return zeta1 + zeta2 - zm - zn;
}

#define PF 4   // prefetch ring depth: ~24 outstanding loads/lane

__global__ __launch_bounds__(256) void scan_kernel(
    const float* __restrict__ Cws, float* __restrict__ out, float* __restrict__ carry,
    int t0, int TC, int isFirst, int isLast) {
  int ij = blockIdx.y * 256 + threadIdx.x;
  if (ij >= L2Q) return;
  int b = blockIdx.x;
  int j = ij % 51;
  const float* base = Cws + (size_t)b * TC * NPAD;  // chunk-local rows
  float mu_p, var_p;
  int tstart;
  Vals ring[PF];
  if (isFirst) {
    Vals v0 = ldvals(base, ij, j);
    Vals v1 = ldvals(base + NPAD, ij, j);
    float mu_c, var_c;
    float sc0 = merge2<true>(v0, v0.smu, v0.svar, mu_c, var_c);
    float sp0 = merge2<false>(v1, mu_c, var_c, mu_p, var_p);
    out[(size_t)(b * TQ + 0) * L2Q + ij] = sc0 + sp0 + v0.tw + v0.sw;
    tstart = 1;
    ring[1 & (PF - 1)] = v1;
  } else {
    mu_p = carry[b * L2Q + ij];
    var_p = carry[BQ * L2Q + b * L2Q + ij];
    tstart = t0;
    ring[t0 & (PF - 1)] = ldvals(base, ij, j);
  }
  int tend = t0 + TC;
#pragma unroll
  for (int p = 1; p < PF; ++p) {
    int t = tstart + p;
    if (t < tend) ring[t & (PF - 1)] = ldvals(base + (size_t)(t - t0) * NPAD, ij, j);
  }
#pragma unroll 4
  for (int t = tstart; t < tend; ++t) {
    Vals cur = ring[t & (PF - 1)];
    int tp = t + PF;
    if (tp < tend) ring[tp & (PF - 1)] = ldvals(base + (size_t)(tp - t0) * NPAD, ij, j);
    float vsum = var_p + cur.svar;
    float rv = frcp(vsum);
    float logv = flog(vsum);
    float dmu = mu_p - cur.smu;
    float sc = -0.5f * (LOG2PI_F + logv + dmu * dmu * rv);
    float mu_c = (mu_p * cur.svar + cur.smu * var_p) * rv;
    float var_c = vsum - 0.5f * logv;
    float sp = merge2<false>(cur, mu_c, var_c, mu_p, var_p);
    out[(size_t)(b * TQ + t) * L2Q + ij] = sc + sp + cur.tw + cur.sw;
  }
  if (!isLast) {
    carry[b * L2Q + ij] = mu_p;
    carry[BQ * L2Q + b * L2Q + ij] = var_p;
  }
}

// ---------------------------------------------------------------- launch
extern "C" void kernel_launch(void* const* d_in, const int* in_sizes, int n_in,
                              void* d_out, int out_size, void* d_ws, size_t ws_size,
                              hipStream_t stream) {
  (void)in_sizes; (void)n_in; (void)out_size;
  const float* x      = (const float*)d_in[0];
  const float* Ws_w   = (const float*)d_in[1];
  const float* bs_w   = (const float*)d_in[2];
  const float* Ws_mu  = (const float*)d_in[3];
  const float* bs_mu  = (const float*)d_in[4];
  const float* Ws_var = (const float*)d_in[5];
  const float* bs_var = (const float*)d_in[6];
  const float* Wt_w   = (const float*)d_in[7];
  const float* bt_w   = (const float*)d_in[8];
  const float* Wt_mu  = (const float*)d_in[9];
  const float* bt_mu  = (const float*)d_in[10];
  const float* Wt_var = (const float*)d_in[11];
  const float* bt_var = (const float*)d_in[12];
  float* out = (float*)d_out;

  char* ws = (char*)d_ws;
  const size_t szA = (size_t)4096 * KQ * 2;          // 12,582,912 (256-aligned)
  const size_t szB = (size_t)NPAD * KQ * 2;          // 48,758,784 (256-aligned)
  const size_t szCar = ((size_t)BQ * L2Q * 2 * 4 + 255) & ~(size_t)255;
  u16* Abf = (u16*)ws;
  u16* BTb = (u16*)(ws + szA);
  float* carry = (float*)(ws + szA + szB);
  size_t offC = szA + szB + szCar;
  float* Cws = (float*)(ws + offC);

  // chunk T so the phase-1 buffer fits in ws
  int TC = 256;
  while (TC > 8 && offC + (size_t)BQ * TC * NPAD * 4 > ws_size) TC >>= 1;
  int lgTC = 31 - __builtin_clz((unsigned)TC);
  int nch = TQ / TC;

  build_a_kernel<<<dim3((4096 * 512) / 256), dim3(256), 0, stream>>>(x, Abf);
  build_b_kernel<<<dim3(NPAD / 256, DQ / 8), dim3(256), 0, stream>>>(
      Ws_w, Ws_mu, Ws_var, Wt_w, Wt_mu, Wt_var, BTb);
  for (int c = 0; c < nch; ++c) {
    int t0 = c * TC;
    gemm_kernel<<<dim3((BQ * TC) / 128, NPAD / 128), dim3(256), 0, stream>>>(
        Abf, BTb, Cws, bs_w, bs_mu, bs_var, bt_w, bt_mu, bt_var, t0, lgTC);
    scan_kernel<<<dim3(BQ, (L2Q + 255) / 256), dim3(256), 0, stream>>>(
        Cws, out, carry, t0, TC, c == 0 ? 1 : 0, c == nch - 1 ? 1 : 0);
  }
}